// Round 1
// baseline (332.393 us; speedup 1.0000x reference)
//
#include <hip/hip_runtime.h>
#include <stdint.h>

typedef unsigned short u16;
typedef __attribute__((ext_vector_type(8))) short   short8;   // 8 x bf16 bits (4 VGPR)
typedef __attribute__((ext_vector_type(8))) u16     ushort8;
typedef __attribute__((ext_vector_type(4))) float   f32x4;

#define SEQ   2048
#define NH    16
#define HD    64
#define DM    1024
#define ROWS  8192   // B*S
#define BHN   64     // B*H

// round-to-nearest-even f32 -> bf16 (inputs are sane, no NaN handling needed)
__device__ __forceinline__ u16 f2bf(float f){
  union { float f; uint32_t u; } v; v.f = f;
  return (u16)((v.u + 0x7fffu + ((v.u >> 16) & 1u)) >> 16);
}

#define GAS(p) ((const __attribute__((address_space(1))) void*)(p))
#define LAS(p) ((__attribute__((address_space(3))) void*)(p))

// ---------------------------------------------------------------- convert x
__global__ void conv_bf16_kernel(const float* __restrict__ in, u16* __restrict__ out, int n8){
  int i = blockIdx.x * blockDim.x + threadIdx.x;
  if (i >= n8) return;
  const float4* p = (const float4*)in + (size_t)i * 2;
  float4 a = p[0], b = p[1];
  ushort8 o;
  o[0]=f2bf(a.x); o[1]=f2bf(a.y); o[2]=f2bf(a.z); o[3]=f2bf(a.w);
  o[4]=f2bf(b.x); o[5]=f2bf(b.y); o[6]=f2bf(b.z); o[7]=f2bf(b.w);
  *(ushort8*)(out + (size_t)i * 8) = o;
}

// ------------------------------------------- transpose+convert  [R][C] f32 -> [C][R] bf16
__global__ void transpose_conv_kernel(const float* __restrict__ in, u16* __restrict__ out,
                                      int R, int C){
  __shared__ float tile[32][33];
  int c0 = blockIdx.x * 32, r0 = blockIdx.y * 32;
  int tx = threadIdx.x & 31, ty = threadIdx.x >> 5;  // 256 thr: 32x8
  #pragma unroll
  for (int i = 0; i < 4; i++)
    tile[ty + 8*i][tx] = in[(size_t)(r0 + ty + 8*i) * C + c0 + tx];
  __syncthreads();
  #pragma unroll
  for (int i = 0; i < 4; i++)
    out[(size_t)(c0 + ty + 8*i) * R + r0 + tx] = f2bf(tile[tx][ty + 8*i]);
}

// ---------------------------------------------------------------- GEMM
// C[m][n] = sum_k A[m][k] * Bt[n][k]  (+bias[n]); A:[M][1024] bf16, Bt:[N][1024] bf16
// MODE 0: scatter QKV epilogue.  MODE 1: fp32 C + bias.
#define BM 128
#define BN 128
#define BK 64

template<int MODE>
__global__ __launch_bounds__(256, 2) void gemm_kernel(
    const u16* __restrict__ A, const u16* __restrict__ Bt, const float* __restrict__ bias,
    u16* __restrict__ Qo, u16* __restrict__ Ko, u16* __restrict__ Vto,
    float* __restrict__ Cout)
{
  __shared__ __align__(16) u16 As[BM * BK];  // rows of 64 bf16 (128B), XOR-swizzled
  __shared__ __align__(16) u16 Bs[BN * BK];
  const int tid  = threadIdx.x;
  const int lane = tid & 63, wv = tid >> 6;
  const int wr = wv >> 1, wc = wv & 1;             // 2x2 wave grid, 64x64 per wave
  const int m0 = blockIdx.y * BM, n0 = blockIdx.x * BN;
  const int K = 1024;

  f32x4 acc[4][4] = {};

  for (int k0 = 0; k0 < K; k0 += BK) {
    // stage A (16KB) + B (16KB): 4 issues each, 256 thr x 16B, inverse-swizzled source
    #pragma unroll
    for (int i = 0; i < 4; i++) {
      int f = (i * 256 + tid) * 16;
      int row = f >> 7, inrow = f & 127;
      int src = inrow ^ ((row & 7) << 4);          // involution
      const u16* ga = A  + (size_t)(m0 + row) * K + k0 + (src >> 1);
      __builtin_amdgcn_global_load_lds(GAS(ga), LAS((char*)As + (i*256 + (wv<<6))*16), 16, 0, 0);
      const u16* gb = Bt + (size_t)(n0 + row) * K + k0 + (src >> 1);
      __builtin_amdgcn_global_load_lds(GAS(gb), LAS((char*)Bs + (i*256 + (wv<<6))*16), 16, 0, 0);
    }
    __syncthreads();
    #pragma unroll
    for (int kk = 0; kk < 2; kk++) {
      short8 af[4], bfr[4];
      #pragma unroll
      for (int i = 0; i < 4; i++) {
        int row = wr*64 + i*16 + (lane & 15);
        int kb  = (kk*64 + 16*(lane >> 4)) ^ ((row & 7) << 4);
        af[i] = *(const short8*)((const char*)As + row*128 + kb);
      }
      #pragma unroll
      for (int j = 0; j < 4; j++) {
        int row = wc*64 + j*16 + (lane & 15);
        int kb  = (kk*64 + 16*(lane >> 4)) ^ ((row & 7) << 4);
        bfr[j] = *(const short8*)((const char*)Bs + row*128 + kb);
      }
      #pragma unroll
      for (int i = 0; i < 4; i++)
        #pragma unroll
        for (int j = 0; j < 4; j++)
          acc[i][j] = __builtin_amdgcn_mfma_f32_16x16x32_bf16(af[i], bfr[j], acc[i][j], 0, 0, 0);
    }
    __syncthreads();
  }

  // epilogue: C/D layout col=lane&15, row=(lane>>4)*4+r  [m89-verified]
  if (MODE == 0) {
    const int part = n0 >> 10;                      // 0=q 1=k 2=v (tile never crosses)
    #pragma unroll
    for (int i = 0; i < 4; i++) {
      int row = m0 + wr*64 + i*16 + ((lane >> 4) << 2);
      int b = row >> 11, s = row & 2047;
      #pragma unroll
      for (int j = 0; j < 4; j++) {
        int col = n0 + wc*64 + j*16 + (lane & 15);
        int cn = col & 1023, h = cn >> 6, d = cn & 63;
        int bh = b * NH + h;
        #pragma unroll
        for (int r = 0; r < 4; r++) {
          float v = acc[i][j][r] + bias[col];
          int ss = s + r;
          if (part == 0)      Qo [((size_t)bh*SEQ + ss)*HD + d] = f2bf(v * 0.125f); // fold 1/sqrt(64), exact
          else if (part == 1) Ko [((size_t)bh*SEQ + ss)*HD + d] = f2bf(v);
          else                Vto[((size_t)bh*HD  + d)*SEQ + ss] = f2bf(v);
        }
      }
    }
  } else {
    #pragma unroll
    for (int i = 0; i < 4; i++) {
      int row = m0 + wr*64 + i*16 + ((lane >> 4) << 2);
      #pragma unroll
      for (int j = 0; j < 4; j++) {
        int col = n0 + wc*64 + j*16 + (lane & 15);
        float bv = bias[col];
        #pragma unroll
        for (int r = 0; r < 4; r++)
          Cout[(size_t)(row + r) * DM + col] = acc[i][j][r] + bv;
      }
    }
  }
}

// ---------------------------------------------------------------- flash attention
// Q:[BH][S][64] bf16 (pre-scaled), K:[BH][S][64], Vt:[BH][64][S], O:[ROWS][1024] bf16
__global__ __launch_bounds__(256, 2) void attn_kernel(
    const u16* __restrict__ Q, const u16* __restrict__ Kg,
    const u16* __restrict__ Vt, u16* __restrict__ O)
{
  __shared__ __align__(16) u16 Ks[64 * 64];
  __shared__ __align__(16) u16 Vs[64 * 64];
  __shared__ __align__(16) u16 Ps[4][16 * 80];     // per-wave P, pitch 80
  const int tid = threadIdx.x, lane = tid & 63, wv = tid >> 6;
  const int bh = blockIdx.y, q0 = blockIdx.x * 64;

  short8 qf[2];
  {
    int qrow = q0 + wv*16 + (lane & 15);
    const u16* qp = Q + ((size_t)bh*SEQ + qrow)*HD + 8*(lane >> 4);
    qf[0] = *(const short8*)qp;
    qf[1] = *(const short8*)(qp + 32);
  }
  float m[4], lsum[4];
  f32x4 oacc[4];
  #pragma unroll
  for (int r = 0; r < 4; r++){ m[r] = -1e30f; lsum[r] = 0.f; }
  #pragma unroll
  for (int dt = 0; dt < 4; dt++) oacc[dt] = (f32x4){0.f,0.f,0.f,0.f};

  for (int t = 0; t < SEQ/64; ++t) {
    int kb0 = t * 64;
    #pragma unroll
    for (int i = 0; i < 2; i++) {                   // 8KB each: 2 issues
      int f = (i * 256 + tid) * 16;
      int row = f >> 7, inrow = f & 127;
      int src = inrow ^ ((row & 7) << 4);
      const u16* gk = Kg + ((size_t)bh*SEQ + kb0 + row)*HD + (src >> 1);
      __builtin_amdgcn_global_load_lds(GAS(gk), LAS((char*)Ks + (i*256 + (wv<<6))*16), 16, 0, 0);
      const u16* gv = Vt + ((size_t)bh*HD + row)*SEQ + kb0 + (src >> 1);
      __builtin_amdgcn_global_load_lds(GAS(gv), LAS((char*)Vs + (i*256 + (wv<<6))*16), 16, 0, 0);
    }
    __syncthreads();

    // scores: 16 q-rows x 64 keys per wave
    f32x4 sc[4];
    #pragma unroll
    for (int c = 0; c < 4; c++) {
      sc[c] = (f32x4){0.f,0.f,0.f,0.f};
      #pragma unroll
      for (int kk = 0; kk < 2; kk++) {
        int row = c*16 + (lane & 15);
        int kb  = (kk*64 + 16*(lane >> 4)) ^ ((row & 7) << 4);
        short8 kf = *(const short8*)((const char*)Ks + row*128 + kb);
        sc[c] = __builtin_amdgcn_mfma_f32_16x16x32_bf16(qf[kk], kf, sc[c], 0, 0, 0);
      }
    }

    // wave-parallel online softmax (rows (lane>>4)*4+r, cols spread over lane&15 x 4 tiles)
    float pv[4][4];
    #pragma unroll
    for (int r = 0; r < 4; r++) {
      float mx = fmaxf(fmaxf(sc[0][r], sc[1][r]), fmaxf(sc[2][r], sc[3][r]));
      mx = fmaxf(mx, __shfl_xor(mx, 1));
      mx = fmaxf(mx, __shfl_xor(mx, 2));
      mx = fmaxf(mx, __shfl_xor(mx, 4));
      mx = fmaxf(mx, __shfl_xor(mx, 8));
      float mn = fmaxf(m[r], mx);
      float al = __expf(m[r] - mn);
      float sum = 0.f;
      #pragma unroll
      for (int c = 0; c < 4; c++) { float p = __expf(sc[c][r] - mn); pv[c][r] = p; sum += p; }
      sum += __shfl_xor(sum, 1);
      sum += __shfl_xor(sum, 2);
      sum += __shfl_xor(sum, 4);
      sum += __shfl_xor(sum, 8);
      lsum[r] = lsum[r] * al + sum;
      m[r] = mn;
      #pragma unroll
      for (int dt = 0; dt < 4; dt++) oacc[dt][r] *= al;
    }

    // P -> wave-private LDS (C-layout write), then read as A-fragments
    u16* pw = &Ps[wv][0];
    #pragma unroll
    for (int r = 0; r < 4; r++) {
      int rr = (lane >> 4) * 4 + r;
      #pragma unroll
      for (int c = 0; c < 4; c++)
        pw[rr*80 + c*16 + (lane & 15)] = f2bf(pv[c][r]);
    }
    asm volatile("" ::: "memory");                  // keep DS write->read ordered (DS FIFO per wave)

    short8 pa[2];
    #pragma unroll
    for (int jb = 0; jb < 2; jb++)
      pa[jb] = *(const short8*)((const char*)pw + (lane & 15)*160 + jb*64 + 16*(lane >> 4));
    #pragma unroll
    for (int dt = 0; dt < 4; dt++) {
      #pragma unroll
      for (int jb = 0; jb < 2; jb++) {
        int row = dt*16 + (lane & 15);
        int jby = (jb*64 + 16*(lane >> 4)) ^ ((row & 7) << 4);
        short8 vb = *(const short8*)((const char*)Vs + row*128 + jby);
        oacc[dt] = __builtin_amdgcn_mfma_f32_16x16x32_bf16(pa[jb], vb, oacc[dt], 0, 0, 0);
      }
    }
    __syncthreads();
  }

  // epilogue: O[b*S+q][h*64+d] = o/l
  int b = bh >> 4, h = bh & 15;
  #pragma unroll
  for (int r = 0; r < 4; r++) {
    float inv = 1.0f / lsum[r];
    int q = q0 + wv*16 + (lane >> 4) * 4 + r;
    size_t base = ((size_t)(b * SEQ + q)) * DM + h * HD;
    #pragma unroll
    for (int dt = 0; dt < 4; dt++)
      O[base + dt*16 + (lane & 15)] = f2bf(oacc[dt][r] * inv);
  }
}

// ---------------------------------------------------------------- launch
extern "C" void kernel_launch(void* const* d_in, const int* in_sizes, int n_in,
                              void* d_out, int out_size, void* d_ws, size_t ws_size,
                              hipStream_t stream)
{
  const float* x     = (const float*)d_in[0];
  const float* w_qkv = (const float*)d_in[1];
  const float* b_qkv = (const float*)d_in[2];
  const float* w_out = (const float*)d_in[3];
  const float* b_out = (const float*)d_in[4];
  float* out = (float*)d_out;

  char* w = (char*)d_ws;
  u16* xb    = (u16*)(w);                  // 16,777,216 B
  u16* wqkvT = (u16*)(w + 16777216);       //  6,291,456 B
  u16* woutT = (u16*)(w + 23068672);       //  2,097,152 B
  u16* Qw    = (u16*)(w + 25165824);       // 16,777,216 B
  u16* Kw    = (u16*)(w + 41943040);       // 16,777,216 B
  u16* Vtw   = (u16*)(w + 58720256);       // 16,777,216 B
  u16* Ow    = (u16*)(w + 75497472);       // 16,777,216 B  (total 92,274,688 B)

  conv_bf16_kernel<<<dim3(4096), dim3(256), 0, stream>>>(x, xb, ROWS * DM / 8);
  transpose_conv_kernel<<<dim3(96, 32), dim3(256), 0, stream>>>(w_qkv, wqkvT, 1024, 3072);
  transpose_conv_kernel<<<dim3(32, 32), dim3(256), 0, stream>>>(w_out, woutT, 1024, 1024);

  gemm_kernel<0><<<dim3(24, 64), dim3(256), 0, stream>>>(xb, wqkvT, b_qkv, Qw, Kw, Vtw, nullptr);
  attn_kernel<<<dim3(SEQ/64, BHN), dim3(256), 0, stream>>>(Qw, Kw, Vtw, Ow);
  gemm_kernel<1><<<dim3(8, 64), dim3(256), 0, stream>>>(Ow, woutT, b_out, nullptr, nullptr, nullptr, out);
}

// Round 2
// 236.797 us; speedup vs baseline: 1.4037x; 1.4037x over previous
//
#include <hip/hip_runtime.h>
#include <stdint.h>

typedef unsigned short u16;
typedef __attribute__((ext_vector_type(8))) short   short8;   // 8 x bf16 bits (4 VGPR)
typedef __attribute__((ext_vector_type(8))) u16     ushort8;
typedef __attribute__((ext_vector_type(4))) float   f32x4;
typedef __attribute__((ext_vector_type(16))) float  f32x16;
typedef __attribute__((ext_vector_type(2))) unsigned int u32x2;

#define SEQ   2048
#define NH    16
#define HD    64
#define DM    1024
#define ROWS  8192   // B*S
#define BHN   64     // B*H

// round-to-nearest-even f32 -> bf16
__device__ __forceinline__ u16 f2bf(float f){
  union { float f; uint32_t u; } v; v.f = f;
  return (u16)((v.u + 0x7fffu + ((v.u >> 16) & 1u)) >> 16);
}

__device__ __forceinline__ unsigned cvtpk(float a, float b){
  unsigned r;
  asm("v_cvt_pk_bf16_f32 %0, %1, %2" : "=v"(r) : "v"(a), "v"(b));
  return r;
}

#define GAS(p) ((const __attribute__((address_space(1))) void*)(p))
#define LAS(p) ((__attribute__((address_space(3))) void*)(p))

// ---------------------------------------------------------------- convert x
__global__ void conv_bf16_kernel(const float* __restrict__ in, u16* __restrict__ out, int n8){
  int i = blockIdx.x * blockDim.x + threadIdx.x;
  if (i >= n8) return;
  const float4* p = (const float4*)in + (size_t)i * 2;
  float4 a = p[0], b = p[1];
  ushort8 o;
  o[0]=f2bf(a.x); o[1]=f2bf(a.y); o[2]=f2bf(a.z); o[3]=f2bf(a.w);
  o[4]=f2bf(b.x); o[5]=f2bf(b.y); o[6]=f2bf(b.z); o[7]=f2bf(b.w);
  *(ushort8*)(out + (size_t)i * 8) = o;
}

// ------------------------------------------- transpose+convert  [R][C] f32 -> [C][R] bf16
__global__ void transpose_conv_kernel(const float* __restrict__ in, u16* __restrict__ out,
                                      int R, int C){
  __shared__ float tile[32][33];
  int c0 = blockIdx.x * 32, r0 = blockIdx.y * 32;
  int tx = threadIdx.x & 31, ty = threadIdx.x >> 5;  // 256 thr: 32x8
  #pragma unroll
  for (int i = 0; i < 4; i++)
    tile[ty + 8*i][tx] = in[(size_t)(r0 + ty + 8*i) * C + c0 + tx];
  __syncthreads();
  #pragma unroll
  for (int i = 0; i < 4; i++)
    out[(size_t)(c0 + ty + 8*i) * R + r0 + tx] = f2bf(tile[tx][ty + 8*i]);
}

// ---------------------------------------------------------------- GEMM (round-1, verified)
#define BM 128
#define BN 128
#define BK 64

template<int MODE>
__global__ __launch_bounds__(256, 2) void gemm_kernel(
    const u16* __restrict__ A, const u16* __restrict__ Bt, const float* __restrict__ bias,
    u16* __restrict__ Qo, u16* __restrict__ Ko, u16* __restrict__ Vto,
    float* __restrict__ Cout)
{
  __shared__ __align__(16) u16 As[BM * BK];
  __shared__ __align__(16) u16 Bs[BN * BK];
  const int tid  = threadIdx.x;
  const int lane = tid & 63, wv = tid >> 6;
  const int wr = wv >> 1, wc = wv & 1;
  const int m0 = blockIdx.y * BM, n0 = blockIdx.x * BN;
  const int K = 1024;

  f32x4 acc[4][4] = {};

  for (int k0 = 0; k0 < K; k0 += BK) {
    #pragma unroll
    for (int i = 0; i < 4; i++) {
      int f = (i * 256 + tid) * 16;
      int row = f >> 7, inrow = f & 127;
      int src = inrow ^ ((row & 7) << 4);
      const u16* ga = A  + (size_t)(m0 + row) * K + k0 + (src >> 1);
      __builtin_amdgcn_global_load_lds(GAS(ga), LAS((char*)As + (i*256 + (wv<<6))*16), 16, 0, 0);
      const u16* gb = Bt + (size_t)(n0 + row) * K + k0 + (src >> 1);
      __builtin_amdgcn_global_load_lds(GAS(gb), LAS((char*)Bs + (i*256 + (wv<<6))*16), 16, 0, 0);
    }
    __syncthreads();
    #pragma unroll
    for (int kk = 0; kk < 2; kk++) {
      short8 af[4], bfr[4];
      #pragma unroll
      for (int i = 0; i < 4; i++) {
        int row = wr*64 + i*16 + (lane & 15);
        int kb  = (kk*64 + 16*(lane >> 4)) ^ ((row & 7) << 4);
        af[i] = *(const short8*)((const char*)As + row*128 + kb);
      }
      #pragma unroll
      for (int j = 0; j < 4; j++) {
        int row = wc*64 + j*16 + (lane & 15);
        int kb  = (kk*64 + 16*(lane >> 4)) ^ ((row & 7) << 4);
        bfr[j] = *(const short8*)((const char*)Bs + row*128 + kb);
      }
      #pragma unroll
      for (int i = 0; i < 4; i++)
        #pragma unroll
        for (int j = 0; j < 4; j++)
          acc[i][j] = __builtin_amdgcn_mfma_f32_16x16x32_bf16(af[i], bfr[j], acc[i][j], 0, 0, 0);
    }
    __syncthreads();
  }

  if (MODE == 0) {
    const int part = n0 >> 10;
    #pragma unroll
    for (int i = 0; i < 4; i++) {
      int row = m0 + wr*64 + i*16 + ((lane >> 4) << 2);
      int b = row >> 11, s = row & 2047;
      #pragma unroll
      for (int j = 0; j < 4; j++) {
        int col = n0 + wc*64 + j*16 + (lane & 15);
        int cn = col & 1023, h = cn >> 6, d = cn & 63;
        int bh = b * NH + h;
        #pragma unroll
        for (int r = 0; r < 4; r++) {
          float v = acc[i][j][r] + bias[col];
          int ss = s + r;
          // Q pre-scale folds 1/sqrt(64) * log2(e) so attention works in exp2 domain
          if (part == 0)      Qo [((size_t)bh*SEQ + ss)*HD + d] = f2bf(v * 0.18033688011f);
          else if (part == 1) Ko [((size_t)bh*SEQ + ss)*HD + d] = f2bf(v);
          else                Vto[((size_t)bh*HD  + d)*SEQ + ss] = f2bf(v);
        }
      }
    }
  } else {
    #pragma unroll
    for (int i = 0; i < 4; i++) {
      int row = m0 + wr*64 + i*16 + ((lane >> 4) << 2);
      #pragma unroll
      for (int j = 0; j < 4; j++) {
        int col = n0 + wc*64 + j*16 + (lane & 15);
        float bv = bias[col];
        #pragma unroll
        for (int r = 0; r < 4; r++)
          Cout[(size_t)(row + r) * DM + col] = acc[i][j][r] + bv;
      }
    }
  }
}

// ---------------------------------------------------------------- flash attention (R2)
// Swapped QK^T (mfma(K,Q)), 32x32x16 MFMA, wave-max online softmax with defer-max,
// P via swizzled row-major LDS bounce, double-buffered K/V staging.
// Q:[BH][S][64] bf16 (pre-scaled by 0.125*log2e), K:[BH][S][64], Vt:[BH][64][S],
// O:[ROWS][1024] bf16.
#define STAGE(LOFF, T) do { \
    int _row = tid >> 3; \
    int _src = ((tid & 7) << 4) ^ ((_row & 7) << 4); \
    const u16* _gk = Kg + (((size_t)bh * SEQ + (T) * 64 + _row) << 6) + (_src >> 1); \
    __builtin_amdgcn_global_load_lds(GAS(_gk), LAS(lds + (LOFF) + (wv << 10)), 16, 0, 0); \
    const u16* _gv = Vt + ((size_t)(bh * 64 + _row)) * SEQ + (T) * 64 + (_src >> 1); \
    __builtin_amdgcn_global_load_lds(GAS(_gv), LAS(lds + (LOFF) + 8192 + (wv << 10)), 16, 0, 0); \
  } while (0)

#define WAITBAR() do { \
    asm volatile("s_waitcnt vmcnt(0) lgkmcnt(0)" ::: "memory"); \
    __builtin_amdgcn_s_barrier(); \
  } while (0)

#define TILE(BOFF) do { \
    f32x16 s0 = {}, s1 = {}; \
    _Pragma("unroll") \
    for (int kd = 0; kd < 4; kd++) { \
      int ko = (32 * kd + 16 * hi) ^ swz; \
      short8 kf0 = *(const short8*)(lds + (BOFF) + l31 * 128 + ko); \
      short8 kf1 = *(const short8*)(lds + (BOFF) + 4096 + l31 * 128 + ko); \
      s0 = __builtin_amdgcn_mfma_f32_32x32x16_bf16(kf0, qf[kd], s0, 0, 0, 0); \
      s1 = __builtin_amdgcn_mfma_f32_32x32x16_bf16(kf1, qf[kd], s1, 0, 0, 0); \
    } \
    float lmax = s0[0]; \
    _Pragma("unroll") for (int i = 1; i < 16; i++) lmax = fmaxf(lmax, s0[i]); \
    _Pragma("unroll") for (int i = 0; i < 16; i++) lmax = fmaxf(lmax, s1[i]); \
    if (!__all(lmax <= M + 8.0f)) { \
      float Mw = lmax; \
      _Pragma("unroll") for (int d = 1; d < 64; d <<= 1) Mw = fmaxf(Mw, __shfl_xor(Mw, d)); \
      float al = exp2f(M - Mw); \
      M = Mw; lp *= al; \
      _Pragma("unroll") for (int i = 0; i < 16; i++) { oacc0[i] *= al; oacc1[i] *= al; } \
    } \
    _Pragma("unroll") for (int i = 0; i < 16; i++) s0[i] = exp2f(s0[i] - M); \
    _Pragma("unroll") for (int i = 0; i < 16; i++) s1[i] = exp2f(s1[i] - M); \
    float ps = 0.f; \
    _Pragma("unroll") for (int i = 0; i < 16; i++) ps += s0[i] + s1[i]; \
    lp += ps; \
    _Pragma("unroll") \
    for (int t = 0; t < 4; t++) { \
      unsigned a0 = cvtpk(s0[4*t], s0[4*t+1]), a1 = cvtpk(s0[4*t+2], s0[4*t+3]); \
      *(u32x2*)(lds + POFF + l31 * 128 + (((16 * t) ^ swz) + 8 * hi)) = (u32x2){a0, a1}; \
      unsigned b0 = cvtpk(s1[4*t], s1[4*t+1]), b1 = cvtpk(s1[4*t+2], s1[4*t+3]); \
      *(u32x2*)(lds + POFF + l31 * 128 + (((64 + 16 * t) ^ swz) + 8 * hi)) = (u32x2){b0, b1}; \
    } \
    asm volatile("" ::: "memory"); \
    short8 pa[4]; \
    _Pragma("unroll") \
    for (int ki = 0; ki < 4; ki++) \
      pa[ki] = *(const short8*)(lds + POFF + l31 * 128 + ((32 * ki + 16 * hi) ^ swz)); \
    _Pragma("unroll") \
    for (int ki = 0; ki < 4; ki++) { \
      int vo = (32 * ki + 16 * hi) ^ swz; \
      short8 vb0 = *(const short8*)(lds + (BOFF) + 8192 + l31 * 128 + vo); \
      short8 vb1 = *(const short8*)(lds + (BOFF) + 12288 + l31 * 128 + vo); \
      oacc0 = __builtin_amdgcn_mfma_f32_32x32x16_bf16(pa[ki], vb0, oacc0, 0, 0, 0); \
      oacc1 = __builtin_amdgcn_mfma_f32_32x32x16_bf16(pa[ki], vb1, oacc1, 0, 0, 0); \
    } \
  } while (0)

__global__ __launch_bounds__(512, 4) void attn_kernel(
    const u16* __restrict__ Q, const u16* __restrict__ Kg,
    const u16* __restrict__ Vt, u16* __restrict__ O)
{
  // LDS: [0,8K) K buf0, [8K,16K) V buf0, [16K,24K) K buf1, [24K,32K) V buf1,
  //      [32K,64K) per-wave P (4KB each)
  __shared__ __align__(16) char lds[65536];
  const int tid = threadIdx.x, lane = tid & 63, wv = tid >> 6;
  const int l31 = lane & 31, hi = lane >> 5;
  const int swz = (lane & 7) << 4;
  const int POFF = 32768 + wv * 4096;

  // XCD-bijective swizzle: 512 blocks = 8 XCD x 64; each XCD owns 8 whole heads
  int flat = blockIdx.x;
  int nid = (flat & 7) * 64 + (flat >> 3);
  int bh = nid >> 3;
  int q0 = (nid & 7) * 256;

  short8 qf[4];
  {
    int qrow = q0 + wv * 32 + l31;
    const u16* qp = Q + (((size_t)bh * SEQ + qrow) << 6) + hi * 8;
    #pragma unroll
    for (int kd = 0; kd < 4; kd++) qf[kd] = *(const short8*)(qp + kd * 16);
  }

  f32x16 oacc0 = {}, oacc1 = {};
  float M = -1e30f, lp = 0.f;

  STAGE(0, 0);
  WAITBAR();
  for (int t = 0; t < 32; t += 2) {
    STAGE(16384, t + 1);
    TILE(0);
    WAITBAR();
    if (t + 2 < 32) STAGE(0, t + 2);
    TILE(16384);
    WAITBAR();
  }

  // epilogue
  float lfull = lp + __shfl_xor(lp, 32);
  int b = bh >> 4, h = bh & 15;
  int qbase = q0 + wv * 32;
  #pragma unroll
  for (int r = 0; r < 16; r++) {
    int qrow = (r & 3) + 8 * (r >> 2) + 4 * hi;
    float inv = 1.0f / __shfl(lfull, qrow);
    size_t rowb = ((size_t)(b * SEQ + qbase + qrow) << 10) + h * 64 + l31;
    O[rowb]      = f2bf(oacc0[r] * inv);
    O[rowb + 32] = f2bf(oacc1[r] * inv);
  }
}

// ---------------------------------------------------------------- launch
extern "C" void kernel_launch(void* const* d_in, const int* in_sizes, int n_in,
                              void* d_out, int out_size, void* d_ws, size_t ws_size,
                              hipStream_t stream)
{
  const float* x     = (const float*)d_in[0];
  const float* w_qkv = (const float*)d_in[1];
  const float* b_qkv = (const float*)d_in[2];
  const float* w_out = (const float*)d_in[3];
  const float* b_out = (const float*)d_in[4];
  float* out = (float*)d_out;

  char* w = (char*)d_ws;
  u16* xb    = (u16*)(w);                  // 16,777,216 B
  u16* wqkvT = (u16*)(w + 16777216);       //  6,291,456 B
  u16* woutT = (u16*)(w + 23068672);       //  2,097,152 B
  u16* Qw    = (u16*)(w + 25165824);       // 16,777,216 B
  u16* Kw    = (u16*)(w + 41943040);       // 16,777,216 B
  u16* Vtw   = (u16*)(w + 58720256);       // 16,777,216 B
  u16* Ow    = (u16*)(w + 75497472);       // 16,777,216 B

  conv_bf16_kernel<<<dim3(4096), dim3(256), 0, stream>>>(x, xb, ROWS * DM / 8);
  transpose_conv_kernel<<<dim3(96, 32), dim3(256), 0, stream>>>(w_qkv, wqkvT, 1024, 3072);
  transpose_conv_kernel<<<dim3(32, 32), dim3(256), 0, stream>>>(w_out, woutT, 1024, 1024);

  gemm_kernel<0><<<dim3(24, 64), dim3(256), 0, stream>>>(xb, wqkvT, b_qkv, Qw, Kw, Vtw, nullptr);
  attn_kernel<<<dim3(512), dim3(512), 0, stream>>>(Qw, Kw, Vtw, Ow);
  gemm_kernel<1><<<dim3(8, 64), dim3(256), 0, stream>>>(Ow, woutT, b_out, nullptr, nullptr, nullptr, out);
}

// Round 3
// 233.698 us; speedup vs baseline: 1.4223x; 1.0133x over previous
//
#include <hip/hip_runtime.h>
#include <stdint.h>

typedef unsigned short u16;
typedef __attribute__((ext_vector_type(8))) short   short8;   // 8 x bf16 bits (4 VGPR)
typedef __attribute__((ext_vector_type(8))) u16     ushort8;
typedef __attribute__((ext_vector_type(4))) float   f32x4;
typedef __attribute__((ext_vector_type(16))) float  f32x16;
typedef __attribute__((ext_vector_type(4))) unsigned int u32x4;

#define SEQ   2048
#define NH    16
#define HD    64
#define DM    1024
#define ROWS  8192   // B*S
#define BHN   64     // B*H

// round-to-nearest-even f32 -> bf16
__device__ __forceinline__ u16 f2bf(float f){
  union { float f; uint32_t u; } v; v.f = f;
  return (u16)((v.u + 0x7fffu + ((v.u >> 16) & 1u)) >> 16);
}

__device__ __forceinline__ unsigned cvtpk(float a, float b){
  unsigned r;
  asm("v_cvt_pk_bf16_f32 %0, %1, %2" : "=v"(r) : "v"(a), "v"(b));
  return r;
}

// v_permlane32_swap_b32: a.hi32lanes <-> b.lo32lanes
__device__ __forceinline__ void pswap(unsigned &a, unsigned &b){
  asm volatile("v_permlane32_swap_b32 %0, %1" : "+v"(a), "+v"(b));
}

#define GAS(p) ((const __attribute__((address_space(1))) void*)(p))
#define LAS(p) ((__attribute__((address_space(3))) void*)(p))

// ---------------------------------------------------------------- convert x
__global__ void conv_bf16_kernel(const float* __restrict__ in, u16* __restrict__ out, int n8){
  int i = blockIdx.x * blockDim.x + threadIdx.x;
  if (i >= n8) return;
  const float4* p = (const float4*)in + (size_t)i * 2;
  float4 a = p[0], b = p[1];
  ushort8 o;
  o[0]=f2bf(a.x); o[1]=f2bf(a.y); o[2]=f2bf(a.z); o[3]=f2bf(a.w);
  o[4]=f2bf(b.x); o[5]=f2bf(b.y); o[6]=f2bf(b.z); o[7]=f2bf(b.w);
  *(ushort8*)(out + (size_t)i * 8) = o;
}

// ------------------------------------------- transpose+convert  [R][C] f32 -> [C][R] bf16
__global__ void transpose_conv_kernel(const float* __restrict__ in, u16* __restrict__ out,
                                      int R, int C){
  __shared__ float tile[32][33];
  int c0 = blockIdx.x * 32, r0 = blockIdx.y * 32;
  int tx = threadIdx.x & 31, ty = threadIdx.x >> 5;  // 256 thr: 32x8
  #pragma unroll
  for (int i = 0; i < 4; i++)
    tile[ty + 8*i][tx] = in[(size_t)(r0 + ty + 8*i) * C + c0 + tx];
  __syncthreads();
  #pragma unroll
  for (int i = 0; i < 4; i++)
    out[(size_t)(c0 + ty + 8*i) * R + r0 + tx] = f2bf(tile[tx][ty + 8*i]);
}

// ---------------------------------------------------------------- GEMM (round-1, verified)
#define BM 128
#define BN 128
#define BK 64

template<int MODE>
__global__ __launch_bounds__(256, 2) void gemm_kernel(
    const u16* __restrict__ A, const u16* __restrict__ Bt, const float* __restrict__ bias,
    u16* __restrict__ Qo, u16* __restrict__ Ko, u16* __restrict__ Vto,
    float* __restrict__ Cout)
{
  __shared__ __align__(16) u16 As[BM * BK];
  __shared__ __align__(16) u16 Bs[BN * BK];
  const int tid  = threadIdx.x;
  const int lane = tid & 63, wv = tid >> 6;
  const int wr = wv >> 1, wc = wv & 1;
  const int m0 = blockIdx.y * BM, n0 = blockIdx.x * BN;
  const int K = 1024;

  f32x4 acc[4][4] = {};

  for (int k0 = 0; k0 < K; k0 += BK) {
    #pragma unroll
    for (int i = 0; i < 4; i++) {
      int f = (i * 256 + tid) * 16;
      int row = f >> 7, inrow = f & 127;
      int src = inrow ^ ((row & 7) << 4);
      const u16* ga = A  + (size_t)(m0 + row) * K + k0 + (src >> 1);
      __builtin_amdgcn_global_load_lds(GAS(ga), LAS((char*)As + (i*256 + (wv<<6))*16), 16, 0, 0);
      const u16* gb = Bt + (size_t)(n0 + row) * K + k0 + (src >> 1);
      __builtin_amdgcn_global_load_lds(GAS(gb), LAS((char*)Bs + (i*256 + (wv<<6))*16), 16, 0, 0);
    }
    __syncthreads();
    #pragma unroll
    for (int kk = 0; kk < 2; kk++) {
      short8 af[4], bfr[4];
      #pragma unroll
      for (int i = 0; i < 4; i++) {
        int row = wr*64 + i*16 + (lane & 15);
        int kb  = (kk*64 + 16*(lane >> 4)) ^ ((row & 7) << 4);
        af[i] = *(const short8*)((const char*)As + row*128 + kb);
      }
      #pragma unroll
      for (int j = 0; j < 4; j++) {
        int row = wc*64 + j*16 + (lane & 15);
        int kb  = (kk*64 + 16*(lane >> 4)) ^ ((row & 7) << 4);
        bfr[j] = *(const short8*)((const char*)Bs + row*128 + kb);
      }
      #pragma unroll
      for (int i = 0; i < 4; i++)
        #pragma unroll
        for (int j = 0; j < 4; j++)
          acc[i][j] = __builtin_amdgcn_mfma_f32_16x16x32_bf16(af[i], bfr[j], acc[i][j], 0, 0, 0);
    }
    __syncthreads();
  }

  if (MODE == 0) {
    const int part = n0 >> 10;
    #pragma unroll
    for (int i = 0; i < 4; i++) {
      int row = m0 + wr*64 + i*16 + ((lane >> 4) << 2);
      int b = row >> 11, s = row & 2047;
      #pragma unroll
      for (int j = 0; j < 4; j++) {
        int col = n0 + wc*64 + j*16 + (lane & 15);
        int cn = col & 1023, h = cn >> 6, d = cn & 63;
        int bh = b * NH + h;
        #pragma unroll
        for (int r = 0; r < 4; r++) {
          float v = acc[i][j][r] + bias[col];
          int ss = s + r;
          // Q pre-scale folds 1/sqrt(64) * log2(e) so attention works in exp2 domain
          if (part == 0)      Qo [((size_t)bh*SEQ + ss)*HD + d] = f2bf(v * 0.18033688011f);
          else if (part == 1) Ko [((size_t)bh*SEQ + ss)*HD + d] = f2bf(v);
          else                Vto[((size_t)bh*HD  + d)*SEQ + ss] = f2bf(v);
        }
      }
    }
  } else {
    #pragma unroll
    for (int i = 0; i < 4; i++) {
      int row = m0 + wr*64 + i*16 + ((lane >> 4) << 2);
      #pragma unroll
      for (int j = 0; j < 4; j++) {
        int col = n0 + wc*64 + j*16 + (lane & 15);
        float bv = bias[col];
        #pragma unroll
        for (int r = 0; r < 4; r++)
          Cout[(size_t)(row + r) * DM + col] = acc[i][j][r] + bv;
      }
    }
  }
}

// ---------------------------------------------------------------- flash attention (R3)
// Swapped QK^T (mfma(K,Q)), 32x32x16 MFMA, in-register P via cvt_pk + permlane32_swap,
// wave-max online softmax with defer-max, double-buffered K/V staging.
// 256 thr / 4 waves, 32 q-rows per wave. LDS 32KB: K0 V0 K1 V1 (8KB each).
#define STAGE(LOFF, T) do { \
    _Pragma("unroll") \
    for (int _i = 0; _i < 2; _i++) { \
      int _row = _i * 32 + (tid >> 3); \
      int _src = ((tid & 7) << 4) ^ ((_row & 7) << 4); \
      const u16* _gk = Kg + (((size_t)bh * SEQ + (T) * 64 + _row) << 6) + (_src >> 1); \
      __builtin_amdgcn_global_load_lds(GAS(_gk), LAS(lds + (LOFF) + _i * 4096 + (wv << 10)), 16, 0, 0); \
      const u16* _gv = Vt + ((size_t)(bh * 64 + _row)) * SEQ + (T) * 64 + (_src >> 1); \
      __builtin_amdgcn_global_load_lds(GAS(_gv), LAS(lds + (LOFF) + 8192 + _i * 4096 + (wv << 10)), 16, 0, 0); \
    } \
  } while (0)

#define WAITBAR() do { \
    asm volatile("s_waitcnt vmcnt(0) lgkmcnt(0)" ::: "memory"); \
    __builtin_amdgcn_s_barrier(); \
  } while (0)

#define TILE(BOFF) do { \
    f32x16 s0 = {}, s1 = {}; \
    _Pragma("unroll") \
    for (int kd = 0; kd < 4; kd++) { \
      int ko = (32 * kd + 16 * hi) ^ swz; \
      short8 kf0 = *(const short8*)(lds + (BOFF) + l31 * 128 + ko); \
      short8 kf1 = *(const short8*)(lds + (BOFF) + 4096 + l31 * 128 + ko); \
      s0 = __builtin_amdgcn_mfma_f32_32x32x16_bf16(kf0, qf[kd], s0, 0, 0, 0); \
      s1 = __builtin_amdgcn_mfma_f32_32x32x16_bf16(kf1, qf[kd], s1, 0, 0, 0); \
    } \
    float lmax = s0[0]; \
    _Pragma("unroll") for (int i = 1; i < 16; i++) lmax = fmaxf(lmax, s0[i]); \
    _Pragma("unroll") for (int i = 0; i < 16; i++) lmax = fmaxf(lmax, s1[i]); \
    if (!__all(lmax <= M + 8.0f)) { \
      float Mw = lmax; \
      _Pragma("unroll") for (int d = 1; d < 64; d <<= 1) Mw = fmaxf(Mw, __shfl_xor(Mw, d)); \
      float al = exp2f(M - Mw); \
      M = Mw; lp *= al; \
      _Pragma("unroll") for (int i = 0; i < 16; i++) { oacc0[i] *= al; oacc1[i] *= al; } \
    } \
    _Pragma("unroll") for (int i = 0; i < 16; i++) s0[i] = exp2f(s0[i] - M); \
    _Pragma("unroll") for (int i = 0; i < 16; i++) s1[i] = exp2f(s1[i] - M); \
    float ps = 0.f; \
    _Pragma("unroll") for (int i = 0; i < 16; i++) ps += s0[i] + s1[i]; \
    lp += ps; \
    /* in-register P: 16 cvt_pk + 8 permlane32_swap -> 4 A-fragments */ \
    union { u32x4 u; short8 s; } pa[4]; \
    _Pragma("unroll") \
    for (int g = 0; g < 2; g++) { \
      const f32x16& sv = g ? s1 : s0; \
      unsigned a0 = cvtpk(sv[0],  sv[1]),  b0 = cvtpk(sv[4],  sv[5]); \
      unsigned a1 = cvtpk(sv[2],  sv[3]),  b1 = cvtpk(sv[6],  sv[7]); \
      unsigned a2 = cvtpk(sv[8],  sv[9]),  b2 = cvtpk(sv[12], sv[13]); \
      unsigned a3 = cvtpk(sv[10], sv[11]), b3 = cvtpk(sv[14], sv[15]); \
      pswap(a0, b0); pswap(a1, b1); pswap(a2, b2); pswap(a3, b3); \
      pa[2*g].u   = (u32x4){a0, a1, b0, b1}; \
      pa[2*g+1].u = (u32x4){a2, a3, b2, b3}; \
    } \
    _Pragma("unroll") \
    for (int ki = 0; ki < 4; ki++) { \
      int vo = (32 * ki + 16 * hi) ^ swz; \
      short8 vb0 = *(const short8*)(lds + (BOFF) + 8192 + l31 * 128 + vo); \
      short8 vb1 = *(const short8*)(lds + (BOFF) + 12288 + l31 * 128 + vo); \
      oacc0 = __builtin_amdgcn_mfma_f32_32x32x16_bf16(pa[ki].s, vb0, oacc0, 0, 0, 0); \
      oacc1 = __builtin_amdgcn_mfma_f32_32x32x16_bf16(pa[ki].s, vb1, oacc1, 0, 0, 0); \
    } \
  } while (0)

__global__ __launch_bounds__(256, 2) void attn_kernel(
    const u16* __restrict__ Q, const u16* __restrict__ Kg,
    const u16* __restrict__ Vt, u16* __restrict__ O)
{
  // LDS: [0,8K) K buf0, [8K,16K) V buf0, [16K,24K) K buf1, [24K,32K) V buf1
  __shared__ __align__(16) char lds[32768];
  const int tid = threadIdx.x, lane = tid & 63, wv = tid >> 6;
  const int l31 = lane & 31, hi = lane >> 5;
  const int swz = (lane & 7) << 4;

  // XCD-bijective swizzle: 1024 blocks = 8 XCD x 128; each XCD owns 8 whole heads
  int flat = blockIdx.x;
  int nid = (flat & 7) * 128 + (flat >> 3);
  int bh = nid >> 4;
  int q0 = (nid & 15) * 128;

  short8 qf[4];
  {
    int qrow = q0 + wv * 32 + l31;
    const u16* qp = Q + (((size_t)bh * SEQ + qrow) << 6) + hi * 8;
    #pragma unroll
    for (int kd = 0; kd < 4; kd++) qf[kd] = *(const short8*)(qp + kd * 16);
  }

  f32x16 oacc0 = {}, oacc1 = {};
  float M = -1e30f, lp = 0.f;

  STAGE(0, 0);
  WAITBAR();
  for (int t = 0; t < 32; t += 2) {
    STAGE(16384, t + 1);
    TILE(0);
    WAITBAR();
    if (t + 2 < 32) STAGE(0, t + 2);
    TILE(16384);
    WAITBAR();
  }

  // epilogue: D layout col(q-in-tile)=l31, row=(r&3)+8*(r>>2)+4*hi
  float lfull = lp + __shfl_xor(lp, 32);
  int b = bh >> 4, h = bh & 15;
  int qbase = q0 + wv * 32;
  #pragma unroll
  for (int r = 0; r < 16; r++) {
    int qrow = (r & 3) + 8 * (r >> 2) + 4 * hi;
    float inv = 1.0f / __shfl(lfull, qrow);
    size_t rowb = ((size_t)(b * SEQ + qbase + qrow) << 10) + h * 64 + l31;
    O[rowb]      = f2bf(oacc0[r] * inv);
    O[rowb + 32] = f2bf(oacc1[r] * inv);
  }
}

// ---------------------------------------------------------------- launch
extern "C" void kernel_launch(void* const* d_in, const int* in_sizes, int n_in,
                              void* d_out, int out_size, void* d_ws, size_t ws_size,
                              hipStream_t stream)
{
  const float* x     = (const float*)d_in[0];
  const float* w_qkv = (const float*)d_in[1];
  const float* b_qkv = (const float*)d_in[2];
  const float* w_out = (const float*)d_in[3];
  const float* b_out = (const float*)d_in[4];
  float* out = (float*)d_out;

  char* w = (char*)d_ws;
  u16* xb    = (u16*)(w);                  // 16,777,216 B
  u16* wqkvT = (u16*)(w + 16777216);       //  6,291,456 B
  u16* woutT = (u16*)(w + 23068672);       //  2,097,152 B
  u16* Qw    = (u16*)(w + 25165824);       // 16,777,216 B
  u16* Kw    = (u16*)(w + 41943040);       // 16,777,216 B
  u16* Vtw   = (u16*)(w + 58720256);       // 16,777,216 B
  u16* Ow    = (u16*)(w + 75497472);       // 16,777,216 B

  conv_bf16_kernel<<<dim3(4096), dim3(256), 0, stream>>>(x, xb, ROWS * DM / 8);
  transpose_conv_kernel<<<dim3(96, 32), dim3(256), 0, stream>>>(w_qkv, wqkvT, 1024, 3072);
  transpose_conv_kernel<<<dim3(32, 32), dim3(256), 0, stream>>>(w_out, woutT, 1024, 1024);

  gemm_kernel<0><<<dim3(24, 64), dim3(256), 0, stream>>>(xb, wqkvT, b_qkv, Qw, Kw, Vtw, nullptr);
  attn_kernel<<<dim3(1024), dim3(256), 0, stream>>>(Qw, Kw, Vtw, Ow);
  gemm_kernel<1><<<dim3(8, 64), dim3(256), 0, stream>>>(Ow, woutT, b_out, nullptr, nullptr, nullptr, out);
}